// Round 1
// baseline (333.680 us; speedup 1.0000x reference)
//
#include <hip/hip_runtime.h>
#include <math.h>

// Shapes: B=4096, N=128, D=64, H=256, O=128
// d_out layout (floats): out[B*128] | mem_new[B*128*64] | h_new[B*256] | c_new[B*256]
// ws layout  (floats): read_w[B*128] | read_vec[B*64] | write_w[B*128] | erase[B*64] | add[B*64]

__device__ __forceinline__ float sigf(float v) { return 1.f / (1.f + __expf(-v)); }

// ---------------- K1: read_w = softmax(h @ W_read^T + b_read) ----------------
// grid 128 (32 rows/block), block 256. thread: rq=t>>5 (4 rows), cl=t&31 (4 cols: cl+32j)
__global__ __launch_bounds__(256) void k1_read_attn(
    const float* __restrict__ h, const float* __restrict__ Wr,
    const float* __restrict__ br, float* __restrict__ read_w)
{
    __shared__ float As[32][33];
    __shared__ float Ws[128][33];
    int t = threadIdx.x;
    int b0 = blockIdx.x * 32;
    int rq = t >> 5, cl = t & 31;
    float acc[4][4];
#pragma unroll
    for (int ri = 0; ri < 4; ++ri)
#pragma unroll
        for (int j = 0; j < 4; ++j) acc[ri][j] = br[cl + 32*j];

    for (int kc = 0; kc < 8; ++kc) {
        __syncthreads();
        for (int i = t; i < 32*32; i += 256) {
            int rr = i >> 5, k = i & 31;
            As[rr][k] = h[(size_t)(b0+rr)*256 + kc*32 + k];
        }
        for (int i = t; i < 128*32; i += 256) {
            int n = i >> 5, k = i & 31;
            Ws[n][k] = Wr[(size_t)n*256 + kc*32 + k];
        }
        __syncthreads();
        for (int k = 0; k < 32; ++k) {
            float a[4];
#pragma unroll
            for (int ri = 0; ri < 4; ++ri) a[ri] = As[rq*4+ri][k];
#pragma unroll
            for (int j = 0; j < 4; ++j) {
                float w = Ws[cl + 32*j][k];
#pragma unroll
                for (int ri = 0; ri < 4; ++ri) acc[ri][j] += a[ri] * w;
            }
        }
    }
    // softmax per row over 128 cols spread across the 32 contiguous lanes (half-wave)
#pragma unroll
    for (int ri = 0; ri < 4; ++ri) {
        int row = b0 + rq*4 + ri;
        float m = fmaxf(fmaxf(acc[ri][0], acc[ri][1]), fmaxf(acc[ri][2], acc[ri][3]));
#pragma unroll
        for (int mk = 16; mk >= 1; mk >>= 1) m = fmaxf(m, __shfl_xor(m, mk));
        float e[4]; float s = 0.f;
#pragma unroll
        for (int j = 0; j < 4; ++j) { e[j] = __expf(acc[ri][j] - m); s += e[j]; }
#pragma unroll
        for (int mk = 16; mk >= 1; mk >>= 1) s += __shfl_xor(s, mk);
        float inv = 1.f / s;
#pragma unroll
        for (int j = 0; j < 4; ++j)
            read_w[(size_t)row*128 + cl + 32*j] = e[j] * inv;
    }
}

// ---------------- K2: read_vec[b,d] = sum_n read_w[b,n]*memory[b,n,d] ----------------
// grid 4096 (1 row/block), block 256. float4 streaming.
__global__ __launch_bounds__(256) void k2_read_vec(
    const float* __restrict__ mem, const float* __restrict__ read_w,
    float* __restrict__ rv)
{
    __shared__ float part[16][68];
    int t = threadIdx.x;
    int b = blockIdx.x;
    int np = t >> 4, d4 = t & 15;
    const float4* m4 = (const float4*)(mem + (size_t)b*8192);
    float4 acc = make_float4(0.f, 0.f, 0.f, 0.f);
#pragma unroll
    for (int j = 0; j < 8; ++j) {
        int n = np + 16*j;
        float w = read_w[(size_t)b*128 + n];
        float4 mv = m4[t + 256*j];
        acc.x += w*mv.x; acc.y += w*mv.y; acc.z += w*mv.z; acc.w += w*mv.w;
    }
    part[np][d4*4+0] = acc.x; part[np][d4*4+1] = acc.y;
    part[np][d4*4+2] = acc.z; part[np][d4*4+3] = acc.w;
    __syncthreads();
    if (t < 64) {
        float s = 0.f;
#pragma unroll
        for (int q = 0; q < 16; ++q) s += part[q][t];
        rv[(size_t)b*64 + t] = s;
    }
}

// ---------------- K3: gates GEMM + LSTM pointwise ----------------
// gates(B,4,256) = [x|rv] @ W_ih^T + h @ W_hh^T + b_ih + b_hh
// grid (128 row-tiles, 4 unit-tiles of 64), block 256.
// thread: rq=t>>5 -> 4 rows, cl=t&31 -> units u0+cl+32*ui (ui=0,1), all 4 gates.
__global__ __launch_bounds__(256) void k3_gates_lstm(
    const float* __restrict__ x, const float* __restrict__ rv,
    const float* __restrict__ h, const float* __restrict__ c,
    const float* __restrict__ Wih, const float* __restrict__ Whh,
    const float* __restrict__ bih, const float* __restrict__ bhh,
    float* __restrict__ h_new, float* __restrict__ c_new)
{
    __shared__ float As[32][33];
    __shared__ float Ws[256][33];
    int t = threadIdx.x;
    int b0 = blockIdx.x * 32;
    int u0 = blockIdx.y * 64;
    int rq = t >> 5, cl = t & 31;
    float acc[4][4][2]; // [ri][gate][ui]
#pragma unroll
    for (int ri = 0; ri < 4; ++ri)
#pragma unroll
        for (int g = 0; g < 4; ++g)
#pragma unroll
            for (int ui = 0; ui < 2; ++ui) {
                int R = g*256 + u0 + cl + 32*ui;
                acc[ri][g][ui] = bih[R] + bhh[R];
            }

    for (int kc = 0; kc < 14; ++kc) {
        __syncthreads();
        for (int i = t; i < 32*32; i += 256) {
            int rr = i >> 5, k = i & 31;
            int row = b0 + rr;
            float v;
            if (kc < 4)      v = x [(size_t)row*128 + kc*32 + k];
            else if (kc < 6) v = rv[(size_t)row*64  + (kc-4)*32 + k];
            else             v = h [(size_t)row*256 + (kc-6)*32 + k];
            As[rr][k] = v;
        }
        for (int i = t; i < 256*32; i += 256) {
            int ri = i >> 5, k = i & 31;
            int g = ri >> 6, u = ri & 63;
            int R = g*256 + u0 + u;
            float v;
            if (kc < 6) v = Wih[(size_t)R*192 + kc*32 + k];
            else        v = Whh[(size_t)R*256 + (kc-6)*32 + k];
            Ws[ri][k] = v;
        }
        __syncthreads();
        for (int k = 0; k < 32; ++k) {
            float a[4];
#pragma unroll
            for (int ri = 0; ri < 4; ++ri) a[ri] = As[rq*4+ri][k];
#pragma unroll
            for (int g = 0; g < 4; ++g)
#pragma unroll
                for (int ui = 0; ui < 2; ++ui) {
                    float w = Ws[g*64 + cl + 32*ui][k];
#pragma unroll
                    for (int ri = 0; ri < 4; ++ri) acc[ri][g][ui] += a[ri] * w;
                }
        }
    }
    // LSTM pointwise, write h_new / c_new
#pragma unroll
    for (int ri = 0; ri < 4; ++ri) {
        int row = b0 + rq*4 + ri;
#pragma unroll
        for (int ui = 0; ui < 2; ++ui) {
            int u = u0 + cl + 32*ui;
            float iv = sigf(acc[ri][0][ui]);
            float fv = sigf(acc[ri][1][ui]);
            float gv = tanhf(acc[ri][2][ui]);
            float ov = sigf(acc[ri][3][ui]);
            float cv = fv * c[(size_t)row*256 + u] + iv * gv;
            float hv = ov * tanhf(cv);
            c_new[(size_t)row*256 + u] = cv;
            h_new[(size_t)row*256 + u] = hv;
        }
    }
}

// ---------------- K4: write_w / erase / add heads ----------------
// 256 output cols = [write 128 | erase 64 | add 64], K=256 over h_new.
// grid 128, block 256. thread: rq=t>>5 -> 4 rows, cl=t&31 -> cols cl+32*j (j=0..7)
__global__ __launch_bounds__(256) void k4_heads(
    const float* __restrict__ hn, const float* __restrict__ Ww,
    const float* __restrict__ We, const float* __restrict__ Wa,
    const float* __restrict__ bw, const float* __restrict__ be,
    const float* __restrict__ ba, float* __restrict__ write_w,
    float* __restrict__ erase, float* __restrict__ addv)
{
    __shared__ float As[32][33];
    __shared__ float Ws[256][33];
    int t = threadIdx.x, b0 = blockIdx.x * 32;
    int rq = t >> 5, cl = t & 31;
    float acc[4][8];
#pragma unroll
    for (int ri = 0; ri < 4; ++ri)
#pragma unroll
        for (int j = 0; j < 8; ++j) {
            int cc = cl + 32*j;
            acc[ri][j] = (cc < 128) ? bw[cc] : (cc < 192 ? be[cc-128] : ba[cc-192]);
        }
    for (int kc = 0; kc < 8; ++kc) {
        __syncthreads();
        for (int i = t; i < 32*32; i += 256) {
            int rr = i >> 5, k = i & 31;
            As[rr][k] = hn[(size_t)(b0+rr)*256 + kc*32 + k];
        }
        for (int i = t; i < 256*32; i += 256) {
            int ri = i >> 5, k = i & 31;
            const float* src = (ri < 128) ? &Ww[(size_t)ri*256]
                              : (ri < 192) ? &We[(size_t)(ri-128)*256]
                                           : &Wa[(size_t)(ri-192)*256];
            Ws[ri][k] = src[kc*32 + k];
        }
        __syncthreads();
        for (int k = 0; k < 32; ++k) {
            float a[4];
#pragma unroll
            for (int ri = 0; ri < 4; ++ri) a[ri] = As[rq*4+ri][k];
#pragma unroll
            for (int j = 0; j < 8; ++j) {
                float w = Ws[cl + 32*j][k];
#pragma unroll
                for (int ri = 0; ri < 4; ++ri) acc[ri][j] += a[ri] * w;
            }
        }
    }
#pragma unroll
    for (int ri = 0; ri < 4; ++ri) {
        int row = b0 + rq*4 + ri;
        // softmax over cols 0..127 (j=0..3, spread across 32 lanes)
        float m = fmaxf(fmaxf(acc[ri][0], acc[ri][1]), fmaxf(acc[ri][2], acc[ri][3]));
#pragma unroll
        for (int mk = 16; mk >= 1; mk >>= 1) m = fmaxf(m, __shfl_xor(m, mk));
        float e[4]; float s = 0.f;
#pragma unroll
        for (int j = 0; j < 4; ++j) { e[j] = __expf(acc[ri][j] - m); s += e[j]; }
#pragma unroll
        for (int mk = 16; mk >= 1; mk >>= 1) s += __shfl_xor(s, mk);
        float inv = 1.f / s;
#pragma unroll
        for (int j = 0; j < 4; ++j)
            write_w[(size_t)row*128 + cl + 32*j] = e[j] * inv;
#pragma unroll
        for (int j = 4; j < 6; ++j)
            erase[(size_t)row*64 + cl + 32*(j-4)] = sigf(acc[ri][j]);
#pragma unroll
        for (int j = 6; j < 8; ++j)
            addv[(size_t)row*64 + cl + 32*(j-6)] = tanhf(acc[ri][j]);
    }
}

// ---------------- K6: out = [h_new | read_vec] @ W_out^T + b_out ----------------
// K = 320 (256 h_new + 64 rv), 128 cols. grid 128, block 256.
__global__ __launch_bounds__(256) void k6_out(
    const float* __restrict__ hn, const float* __restrict__ rv,
    const float* __restrict__ Wo, const float* __restrict__ bo,
    float* __restrict__ outp)
{
    __shared__ float As[32][33];
    __shared__ float Ws[128][33];
    int t = threadIdx.x, b0 = blockIdx.x * 32;
    int rq = t >> 5, cl = t & 31;
    float acc[4][4];
#pragma unroll
    for (int ri = 0; ri < 4; ++ri)
#pragma unroll
        for (int j = 0; j < 4; ++j) acc[ri][j] = bo[cl + 32*j];
    for (int kc = 0; kc < 10; ++kc) {
        __syncthreads();
        for (int i = t; i < 32*32; i += 256) {
            int rr = i >> 5, k = i & 31;
            As[rr][k] = (kc < 8) ? hn[(size_t)(b0+rr)*256 + kc*32 + k]
                                 : rv[(size_t)(b0+rr)*64 + (kc-8)*32 + k];
        }
        for (int i = t; i < 128*32; i += 256) {
            int n = i >> 5, k = i & 31;
            Ws[n][k] = Wo[(size_t)n*320 + kc*32 + k];
        }
        __syncthreads();
        for (int k = 0; k < 32; ++k) {
            float a[4];
#pragma unroll
            for (int ri = 0; ri < 4; ++ri) a[ri] = As[rq*4+ri][k];
#pragma unroll
            for (int j = 0; j < 4; ++j) {
                float w = Ws[cl + 32*j][k];
#pragma unroll
                for (int ri = 0; ri < 4; ++ri) acc[ri][j] += a[ri] * w;
            }
        }
    }
#pragma unroll
    for (int ri = 0; ri < 4; ++ri) {
        int row = b0 + rq*4 + ri;
#pragma unroll
        for (int j = 0; j < 4; ++j)
            outp[(size_t)row*128 + cl + 32*j] = acc[ri][j];
    }
}

// ---------------- K5: mem_new = memory*(1 - ww*erase) + ww*add ----------------
// grid 4096 (1 row/block), block 256, float4 streaming.
__global__ __launch_bounds__(256) void k5_mem_update(
    const float* __restrict__ mem, const float* __restrict__ write_w,
    const float* __restrict__ erase, const float* __restrict__ addv,
    float* __restrict__ mem_new)
{
    int t = threadIdx.x; int b = blockIdx.x;
    int np = t >> 4, d0 = (t & 15) * 4;
    const float4* m4 = (const float4*)(mem + (size_t)b*8192);
    float4* o4 = (float4*)(mem_new + (size_t)b*8192);
    float4 e4 = *(const float4*)(erase + (size_t)b*64 + d0);
    float4 a4 = *(const float4*)(addv + (size_t)b*64 + d0);
#pragma unroll
    for (int j = 0; j < 8; ++j) {
        int n = np + 16*j;
        float w = write_w[(size_t)b*128 + n];
        float4 m = m4[t + 256*j];
        float4 r;
        r.x = m.x * (1.f - w*e4.x) + w*a4.x;
        r.y = m.y * (1.f - w*e4.y) + w*a4.y;
        r.z = m.z * (1.f - w*e4.z) + w*a4.z;
        r.w = m.w * (1.f - w*e4.w) + w*a4.w;
        o4[t + 256*j] = r;
    }
}

extern "C" void kernel_launch(void* const* d_in, const int* in_sizes, int n_in,
                              void* d_out, int out_size, void* d_ws, size_t ws_size,
                              hipStream_t stream)
{
    const float* x    = (const float*)d_in[0];
    const float* mem  = (const float*)d_in[1];
    const float* h    = (const float*)d_in[2];
    const float* c    = (const float*)d_in[3];
    const float* Wih  = (const float*)d_in[4];
    const float* Whh  = (const float*)d_in[5];
    const float* bih  = (const float*)d_in[6];
    const float* bhh  = (const float*)d_in[7];
    const float* Wr   = (const float*)d_in[8];
    const float* br   = (const float*)d_in[9];
    const float* Ww   = (const float*)d_in[10];
    const float* bw   = (const float*)d_in[11];
    const float* We   = (const float*)d_in[12];
    const float* be   = (const float*)d_in[13];
    const float* Wa   = (const float*)d_in[14];
    const float* ba   = (const float*)d_in[15];
    const float* Wo   = (const float*)d_in[16];
    const float* bo   = (const float*)d_in[17];

    float* out     = (float*)d_out;
    float* mem_new = out + 524288;            // 4096*128
    float* h_new   = out + 34078720;          // + 4096*128*64
    float* c_new   = out + 35127296;          // + 4096*256

    float* ws      = (float*)d_ws;
    float* read_w  = ws;                      // 4096*128
    float* rv      = ws + 524288;             // 4096*64
    float* write_w = ws + 786432;             // 4096*128
    float* erase   = ws + 1310720;            // 4096*64
    float* addv    = ws + 1572864;            // 4096*64

    k1_read_attn<<<128, 256, 0, stream>>>(h, Wr, br, read_w);
    k2_read_vec<<<4096, 256, 0, stream>>>(mem, read_w, rv);
    k3_gates_lstm<<<dim3(128, 4), 256, 0, stream>>>(x, rv, h, c, Wih, Whh, bih, bhh, h_new, c_new);
    k4_heads<<<128, 256, 0, stream>>>(h_new, Ww, We, Wa, bw, be, ba, write_w, erase, addv);
    k6_out<<<128, 256, 0, stream>>>(h_new, rv, Wo, bo, out);
    k5_mem_update<<<4096, 256, 0, stream>>>(mem, write_w, erase, addv, mem_new);
}

// Round 2
// 124.469 us; speedup vs baseline: 2.6808x; 2.6808x over previous
//
#include <hip/hip_runtime.h>
#include <math.h>

// Shapes: B=4096, N=128, D=64, H=256, O=128
// d_out (floats): out[B*128] | mem_new[B*128*64] | h_new[B*256] | c_new[B*256]
// ws: read_w f32 | write_w f32 | erase f32 | addv f32 | bsum f32 | bh_b f32 | bf16 region:
//     Ag[4096][448]=[x|rv|h], Aout[4096][320]=[h_new|rv], Wg[1024][448], Wr_b[128][256],
//     Wh_b[256][256], Wo_b[128][320]

typedef __attribute__((ext_vector_type(8))) short bf16x8;
typedef __attribute__((ext_vector_type(4))) float f32x4;
typedef __attribute__((ext_vector_type(4))) unsigned short us4;

#define MFMA16(a, b, c) __builtin_amdgcn_mfma_f32_16x16x32_bf16(a, b, c, 0, 0, 0)
#define GLL16(gp, lp) __builtin_amdgcn_global_load_lds( \
    (const __attribute__((address_space(1))) void*)(gp), \
    (__attribute__((address_space(3))) void*)(lp), 16, 0, 0)
#define SW(row, s) ((s) ^ ((row) & 3))

__device__ __forceinline__ float sigf(float v) { return 1.f / (1.f + __expf(-v)); }

__device__ __forceinline__ unsigned short f2bf(float f) {
    unsigned u = __builtin_bit_cast(unsigned, f);
    u = (u + 0x7FFFu + ((u >> 16) & 1u)) >> 16;
    return (unsigned short)u;
}

// ---------------- P0: pack weights to bf16 + combined biases ----------------
__global__ __launch_bounds__(256) void p0_packW(
    const float* __restrict__ Wih, const float* __restrict__ Whh,
    const float* __restrict__ bih, const float* __restrict__ bhh,
    const float* __restrict__ Wr, const float* __restrict__ Ww,
    const float* __restrict__ We, const float* __restrict__ Wa,
    const float* __restrict__ bw, const float* __restrict__ be,
    const float* __restrict__ ba, const float* __restrict__ Wo,
    unsigned short* __restrict__ Wg, float* __restrict__ bsum,
    unsigned short* __restrict__ Wr_b, unsigned short* __restrict__ Wh_b,
    float* __restrict__ bh_b, unsigned short* __restrict__ Wo_b)
{
    int idx = blockIdx.x * 256 + threadIdx.x;
    int stride = gridDim.x * 256;
    for (int i = idx; i < 1024 * 448; i += stride) {
        int r = i / 448, cc = i - r * 448;
        float v = (cc < 192) ? Wih[(size_t)r * 192 + cc] : Whh[(size_t)r * 256 + (cc - 192)];
        Wg[i] = f2bf(v);
    }
    for (int i = idx; i < 1024; i += stride) bsum[i] = bih[i] + bhh[i];
    for (int i = idx; i < 128 * 256; i += stride) Wr_b[i] = f2bf(Wr[i]);
    for (int i = idx; i < 256 * 256; i += stride) {
        int r = i >> 8, cc = i & 255;
        float v = (r < 128) ? Ww[(size_t)r * 256 + cc]
                : (r < 192) ? We[(size_t)(r - 128) * 256 + cc]
                            : Wa[(size_t)(r - 192) * 256 + cc];
        Wh_b[i] = f2bf(v);
    }
    for (int i = idx; i < 256; i += stride)
        bh_b[i] = (i < 128) ? bw[i] : (i < 192 ? be[i - 128] : ba[i - 192]);
    for (int i = idx; i < 128 * 320; i += stride) Wo_b[i] = f2bf(Wo[i]);
}

// ---------------- P1: pack x,h to bf16 into Ag ----------------
__global__ __launch_bounds__(256) void p1_packA(
    const float* __restrict__ x, const float* __restrict__ h,
    unsigned short* __restrict__ Ag)
{
    int idx = blockIdx.x * 256 + threadIdx.x;
    int stride = gridDim.x * 256;
    for (int i = idx; i < 4096 * 96; i += stride) {
        int row = i / 96, j = i - row * 96;
        float4 v = (j < 32) ? ((const float4*)(x + (size_t)row * 128))[j]
                            : ((const float4*)(h + (size_t)row * 256))[j - 32];
        us4 o = { f2bf(v.x), f2bf(v.y), f2bf(v.z), f2bf(v.w) };
        int col = (j < 32) ? j * 4 : 192 + (j - 32) * 4;
        *(us4*)(Ag + (size_t)row * 448 + col) = o;
    }
}

// ---------------- K1: read_w = softmax(h @ Wr^T + br) [MFMA] ----------------
// grid 64, block 256 (4 waves). Wave: rows wid*16..+15, all 128 cols (8 frags). K=256.
__global__ __launch_bounds__(256) void k1_read_attn(
    const unsigned short* __restrict__ Ag, const unsigned short* __restrict__ Wr_b,
    const float* __restrict__ br, float* __restrict__ read_w)
{
    __shared__ unsigned short As[64 * 32];
    __shared__ unsigned short Bs[128 * 32];
    int t = threadIdx.x;
    int wid = t >> 6, lane = t & 63;
    int cl = lane & 15, ks = lane >> 4;
    int b0 = blockIdx.x * 64;

    int arow = t >> 2;
    const unsigned short* aSrc = Ag + (size_t)(b0 + arow) * 448 + 192 + SW(arow, t & 3) * 8;
    unsigned short* aDst = As + wid * 512;
    int r0 = (t >> 2), r1 = 64 + (t >> 2);
    const unsigned short* bSrc0 = Wr_b + (size_t)r0 * 256 + SW(r0, t & 3) * 8;
    const unsigned short* bSrc1 = Wr_b + (size_t)r1 * 256 + SW(r1, t & 3) * 8;
    unsigned short* bDst0 = Bs + wid * 512;
    unsigned short* bDst1 = Bs + 2048 + wid * 512;

    int mr = wid * 16 + cl;
    int aOff = mr * 32 + SW(mr, ks) * 8;
    int bOff[8];
#pragma unroll
    for (int f = 0; f < 8; ++f) { int br_ = f * 16 + cl; bOff[f] = br_ * 32 + SW(br_, ks) * 8; }

    f32x4 acc[8] = {};
    for (int kc = 0; kc < 8; ++kc) {
        __syncthreads();
        GLL16(aSrc, aDst); GLL16(bSrc0, bDst0); GLL16(bSrc1, bDst1);
        aSrc += 32; bSrc0 += 32; bSrc1 += 32;
        __syncthreads();
        bf16x8 a = *(const bf16x8*)(As + aOff);
#pragma unroll
        for (int f = 0; f < 8; ++f)
            acc[f] = MFMA16(a, *(const bf16x8*)(Bs + bOff[f]), acc[f]);
    }

    float bb[8];
#pragma unroll
    for (int f = 0; f < 8; ++f) bb[f] = br[f * 16 + cl];
#pragma unroll
    for (int r = 0; r < 4; ++r) {
        int row = b0 + wid * 16 + ks * 4 + r;
        float v[8];
#pragma unroll
        for (int f = 0; f < 8; ++f) v[f] = acc[f][r] + bb[f];
        float m = v[0];
#pragma unroll
        for (int f = 1; f < 8; ++f) m = fmaxf(m, v[f]);
#pragma unroll
        for (int mk = 8; mk >= 1; mk >>= 1) m = fmaxf(m, __shfl_xor(m, mk));
        float s = 0.f;
#pragma unroll
        for (int f = 0; f < 8; ++f) { v[f] = __expf(v[f] - m); s += v[f]; }
#pragma unroll
        for (int mk = 8; mk >= 1; mk >>= 1) s += __shfl_xor(s, mk);
        float inv = 1.f / s;
#pragma unroll
        for (int f = 0; f < 8; ++f)
            read_w[(size_t)row * 128 + f * 16 + cl] = v[f] * inv;
    }
}

// ---------------- K2: read_vec (streaming) -> bf16 into Ag & Aout ----------------
__global__ __launch_bounds__(256) void k2_read_vec(
    const float* __restrict__ mem, const float* __restrict__ read_w,
    unsigned short* __restrict__ Ag, unsigned short* __restrict__ Aout)
{
    __shared__ float part[16][68];
    int t = threadIdx.x;
    int b = blockIdx.x;
    int np = t >> 4, d4 = t & 15;
    const float4* m4 = (const float4*)(mem + (size_t)b * 8192);
    float4 acc = make_float4(0.f, 0.f, 0.f, 0.f);
#pragma unroll
    for (int j = 0; j < 8; ++j) {
        int n = np + 16 * j;
        float w = read_w[(size_t)b * 128 + n];
        float4 mv = m4[t + 256 * j];
        acc.x += w * mv.x; acc.y += w * mv.y; acc.z += w * mv.z; acc.w += w * mv.w;
    }
    part[np][d4 * 4 + 0] = acc.x; part[np][d4 * 4 + 1] = acc.y;
    part[np][d4 * 4 + 2] = acc.z; part[np][d4 * 4 + 3] = acc.w;
    __syncthreads();
    if (t < 64) {
        float s = 0.f;
#pragma unroll
        for (int q = 0; q < 16; ++q) s += part[q][t];
        unsigned short bv = f2bf(s);
        Ag[(size_t)b * 448 + 128 + t] = bv;
        Aout[(size_t)b * 320 + 256 + t] = bv;
    }
}

// ---------------- K3: gates GEMM [MFMA] + LSTM pointwise ----------------
// grid (64,4), block 256. Block: 64 rows x 64 units x 4 gates. K=448.
// Wave: rows wid*16..+15; acc[uf 0..3][g 0..3] over units u0+uf*16+cl.
__global__ __launch_bounds__(256) void k3_gates_mfma(
    const unsigned short* __restrict__ Ag, const unsigned short* __restrict__ Wg,
    const float* __restrict__ bsum, const float* __restrict__ c,
    float* __restrict__ h_new, float* __restrict__ c_new,
    unsigned short* __restrict__ Aout)
{
    __shared__ unsigned short As[64 * 32];
    __shared__ unsigned short Bs[256 * 32];
    int t = threadIdx.x;
    int wid = t >> 6, lane = t & 63;
    int cl = lane & 15, ks = lane >> 4;
    int b0 = blockIdx.x * 64;
    int u0 = blockIdx.y * 64;

    int arow = t >> 2;
    const unsigned short* aSrc = Ag + (size_t)(b0 + arow) * 448 + SW(arow, t & 3) * 8;
    unsigned short* aDst = As + wid * 512;
    const unsigned short* bSrc[4];
    unsigned short* bDst[4];
#pragma unroll
    for (int j = 0; j < 4; ++j) {
        int i = j * 256 + t;
        int rl = i >> 2;                    // 0..255
        int g = rl >> 6, u = rl & 63;
        bSrc[j] = Wg + (size_t)(g * 256 + u0 + u) * 448 + SW(rl, t & 3) * 8;
        bDst[j] = Bs + (j * 256 + wid * 64) * 8;
    }

    int mr = wid * 16 + cl;
    int aOff = mr * 32 + SW(mr, ks) * 8;
    int bOff[4][4];
#pragma unroll
    for (int g = 0; g < 4; ++g)
#pragma unroll
        for (int uf = 0; uf < 4; ++uf) {
            int br_ = g * 64 + uf * 16 + cl;
            bOff[g][uf] = br_ * 32 + SW(br_, ks) * 8;
        }

    f32x4 acc[4][4] = {};  // [uf][g]
    for (int kc = 0; kc < 14; ++kc) {
        __syncthreads();
        GLL16(aSrc, aDst);
        GLL16(bSrc[0], bDst[0]); GLL16(bSrc[1], bDst[1]);
        GLL16(bSrc[2], bDst[2]); GLL16(bSrc[3], bDst[3]);
        aSrc += 32;
#pragma unroll
        for (int j = 0; j < 4; ++j) bSrc[j] += 32;
        __syncthreads();
        bf16x8 a = *(const bf16x8*)(As + aOff);
#pragma unroll
        for (int g = 0; g < 4; ++g)
#pragma unroll
            for (int uf = 0; uf < 4; ++uf)
                acc[uf][g] = MFMA16(a, *(const bf16x8*)(Bs + bOff[g][uf]), acc[uf][g]);
    }

#pragma unroll
    for (int uf = 0; uf < 4; ++uf) {
        int unit = u0 + uf * 16 + cl;
        float bi = bsum[unit], bf_ = bsum[256 + unit];
        float bg = bsum[512 + unit], bo_ = bsum[768 + unit];
#pragma unroll
        for (int r = 0; r < 4; ++r) {
            int row = b0 + wid * 16 + ks * 4 + r;
            float iv = sigf(acc[uf][0][r] + bi);
            float fv = sigf(acc[uf][1][r] + bf_);
            float gv = tanhf(acc[uf][2][r] + bg);
            float ov = sigf(acc[uf][3][r] + bo_);
            float cv = fv * c[(size_t)row * 256 + unit] + iv * gv;
            float hv = ov * tanhf(cv);
            c_new[(size_t)row * 256 + unit] = cv;
            h_new[(size_t)row * 256 + unit] = hv;
            Aout[(size_t)row * 320 + unit] = f2bf(hv);
        }
    }
}

// ---------------- K4: heads [MFMA]: cols [write 128 | erase 64 | add 64], K=256 ----------------
// grid 64, block 256. Wave: rows wid*16..+15, 16 frags.
__global__ __launch_bounds__(256) void k4_heads(
    const unsigned short* __restrict__ Aout, const unsigned short* __restrict__ Wh_b,
    const float* __restrict__ bh_b, float* __restrict__ write_w,
    float* __restrict__ erase, float* __restrict__ addv)
{
    __shared__ unsigned short As[64 * 32];
    __shared__ unsigned short Bs[256 * 32];
    int t = threadIdx.x;
    int wid = t >> 6, lane = t & 63;
    int cl = lane & 15, ks = lane >> 4;
    int b0 = blockIdx.x * 64;

    int arow = t >> 2;
    const unsigned short* aSrc = Aout + (size_t)(b0 + arow) * 320 + SW(arow, t & 3) * 8;
    unsigned short* aDst = As + wid * 512;
    const unsigned short* bSrc[4];
    unsigned short* bDst[4];
#pragma unroll
    for (int j = 0; j < 4; ++j) {
        int i = j * 256 + t;
        int rl = i >> 2;
        bSrc[j] = Wh_b + (size_t)rl * 256 + SW(rl, t & 3) * 8;
        bDst[j] = Bs + (j * 256 + wid * 64) * 8;
    }

    int mr = wid * 16 + cl;
    int aOff = mr * 32 + SW(mr, ks) * 8;
    int bOff[16];
#pragma unroll
    for (int f = 0; f < 16; ++f) { int br_ = f * 16 + cl; bOff[f] = br_ * 32 + SW(br_, ks) * 8; }

    f32x4 acc[16] = {};
    for (int kc = 0; kc < 8; ++kc) {
        __syncthreads();
        GLL16(aSrc, aDst);
        GLL16(bSrc[0], bDst[0]); GLL16(bSrc[1], bDst[1]);
        GLL16(bSrc[2], bDst[2]); GLL16(bSrc[3], bDst[3]);
        aSrc += 32;
#pragma unroll
        for (int j = 0; j < 4; ++j) bSrc[j] += 32;
        __syncthreads();
        bf16x8 a = *(const bf16x8*)(As + aOff);
#pragma unroll
        for (int f = 0; f < 16; ++f)
            acc[f] = MFMA16(a, *(const bf16x8*)(Bs + bOff[f]), acc[f]);
    }

    float bb[16];
#pragma unroll
    for (int f = 0; f < 16; ++f) bb[f] = bh_b[f * 16 + cl];
#pragma unroll
    for (int r = 0; r < 4; ++r) {
        int row = b0 + wid * 16 + ks * 4 + r;
        float v[8];
#pragma unroll
        for (int f = 0; f < 8; ++f) v[f] = acc[f][r] + bb[f];
        float m = v[0];
#pragma unroll
        for (int f = 1; f < 8; ++f) m = fmaxf(m, v[f]);
#pragma unroll
        for (int mk = 8; mk >= 1; mk >>= 1) m = fmaxf(m, __shfl_xor(m, mk));
        float s = 0.f;
#pragma unroll
        for (int f = 0; f < 8; ++f) { v[f] = __expf(v[f] - m); s += v[f]; }
#pragma unroll
        for (int mk = 8; mk >= 1; mk >>= 1) s += __shfl_xor(s, mk);
        float inv = 1.f / s;
#pragma unroll
        for (int f = 0; f < 8; ++f)
            write_w[(size_t)row * 128 + f * 16 + cl] = v[f] * inv;
#pragma unroll
        for (int f = 8; f < 12; ++f)
            erase[(size_t)row * 64 + (f - 8) * 16 + cl] = sigf(acc[f][r] + bb[f]);
#pragma unroll
        for (int f = 12; f < 16; ++f)
            addv[(size_t)row * 64 + (f - 12) * 16 + cl] = tanhf(acc[f][r] + bb[f]);
    }
}

// ---------------- K6: out = [h_new|rv] @ Wo^T + bo [MFMA], K=320, N=128 ----------------
__global__ __launch_bounds__(256) void k6_out(
    const unsigned short* __restrict__ Aout, const unsigned short* __restrict__ Wo_b,
    const float* __restrict__ bo, float* __restrict__ outp)
{
    __shared__ unsigned short As[64 * 32];
    __shared__ unsigned short Bs[128 * 32];
    int t = threadIdx.x;
    int wid = t >> 6, lane = t & 63;
    int cl = lane & 15, ks = lane >> 4;
    int b0 = blockIdx.x * 64;

    int arow = t >> 2;
    const unsigned short* aSrc = Aout + (size_t)(b0 + arow) * 320 + SW(arow, t & 3) * 8;
    unsigned short* aDst = As + wid * 512;
    int r0 = (t >> 2), r1 = 64 + (t >> 2);
    const unsigned short* bSrc0 = Wo_b + (size_t)r0 * 320 + SW(r0, t & 3) * 8;
    const unsigned short* bSrc1 = Wo_b + (size_t)r1 * 320 + SW(r1, t & 3) * 8;
    unsigned short* bDst0 = Bs + wid * 512;
    unsigned short* bDst1 = Bs + 2048 + wid * 512;

    int mr = wid * 16 + cl;
    int aOff = mr * 32 + SW(mr, ks) * 8;
    int bOff[8];
#pragma unroll
    for (int f = 0; f < 8; ++f) { int br_ = f * 16 + cl; bOff[f] = br_ * 32 + SW(br_, ks) * 8; }

    f32x4 acc[8] = {};
    for (int kc = 0; kc < 10; ++kc) {
        __syncthreads();
        GLL16(aSrc, aDst); GLL16(bSrc0, bDst0); GLL16(bSrc1, bDst1);
        aSrc += 32; bSrc0 += 32; bSrc1 += 32;
        __syncthreads();
        bf16x8 a = *(const bf16x8*)(As + aOff);
#pragma unroll
        for (int f = 0; f < 8; ++f)
            acc[f] = MFMA16(a, *(const bf16x8*)(Bs + bOff[f]), acc[f]);
    }

    float bb[8];
#pragma unroll
    for (int f = 0; f < 8; ++f) bb[f] = bo[f * 16 + cl];
#pragma unroll
    for (int r = 0; r < 4; ++r) {
        int row = b0 + wid * 16 + ks * 4 + r;
#pragma unroll
        for (int f = 0; f < 8; ++f)
            outp[(size_t)row * 128 + f * 16 + cl] = acc[f][r] + bb[f];
    }
}

// ---------------- K5: mem_new = memory*(1 - ww*erase) + ww*add ----------------
__global__ __launch_bounds__(256) void k5_mem_update(
    const float* __restrict__ mem, const float* __restrict__ write_w,
    const float* __restrict__ erase, const float* __restrict__ addv,
    float* __restrict__ mem_new)
{
    int t = threadIdx.x; int b = blockIdx.x;
    int np = t >> 4, d0 = (t & 15) * 4;
    const float4* m4 = (const float4*)(mem + (size_t)b * 8192);
    float4* o4 = (float4*)(mem_new + (size_t)b * 8192);
    float4 e4 = *(const float4*)(erase + (size_t)b * 64 + d0);
    float4 a4 = *(const float4*)(addv + (size_t)b * 64 + d0);
#pragma unroll
    for (int j = 0; j < 8; ++j) {
        int n = np + 16 * j;
        float w = write_w[(size_t)b * 128 + n];
        float4 m = m4[t + 256 * j];
        float4 r;
        r.x = m.x * (1.f - w * e4.x) + w * a4.x;
        r.y = m.y * (1.f - w * e4.y) + w * a4.y;
        r.z = m.z * (1.f - w * e4.z) + w * a4.z;
        r.w = m.w * (1.f - w * e4.w) + w * a4.w;
        o4[t + 256 * j] = r;
    }
}

extern "C" void kernel_launch(void* const* d_in, const int* in_sizes, int n_in,
                              void* d_out, int out_size, void* d_ws, size_t ws_size,
                              hipStream_t stream)
{
    const float* x    = (const float*)d_in[0];
    const float* mem  = (const float*)d_in[1];
    const float* h    = (const float*)d_in[2];
    const float* c    = (const float*)d_in[3];
    const float* Wih  = (const float*)d_in[4];
    const float* Whh  = (const float*)d_in[5];
    const float* bih  = (const float*)d_in[6];
    const float* bhh  = (const float*)d_in[7];
    const float* Wr   = (const float*)d_in[8];
    const float* br   = (const float*)d_in[9];
    const float* Ww   = (const float*)d_in[10];
    const float* bw   = (const float*)d_in[11];
    const float* We   = (const float*)d_in[12];
    const float* be   = (const float*)d_in[13];
    const float* Wa   = (const float*)d_in[14];
    const float* ba   = (const float*)d_in[15];
    const float* Wo   = (const float*)d_in[16];
    const float* bo   = (const float*)d_in[17];

    float* out     = (float*)d_out;
    float* mem_new = out + 524288;
    float* h_new   = out + 34078720;
    float* c_new   = out + 35127296;

    float* ws      = (float*)d_ws;
    float* read_w  = ws;                       // 4096*128
    float* write_w = ws + 524288;              // 4096*128
    float* erase   = ws + 1048576;             // 4096*64
    float* addv    = ws + 1310720;             // 4096*64
    float* bsum    = ws + 1572864;             // 1024
    float* bh_b    = ws + 1573888;             // 256
    unsigned short* ub   = (unsigned short*)(ws + 1574144);
    unsigned short* Ag   = ub;                 // 4096*448
    unsigned short* Aout = ub + 1835008;       // 4096*320
    unsigned short* Wg   = ub + 3145728;       // 1024*448
    unsigned short* Wr_b = ub + 3604480;       // 128*256
    unsigned short* Wh_b = ub + 3637248;       // 256*256
    unsigned short* Wo_b = ub + 3702784;       // 128*320

    p0_packW<<<512, 256, 0, stream>>>(Wih, Whh, bih, bhh, Wr, Ww, We, Wa, bw, be, ba, Wo,
                                      Wg, bsum, Wr_b, Wh_b, bh_b, Wo_b);
    p1_packA<<<1024, 256, 0, stream>>>(x, h, Ag);
    k1_read_attn<<<64, 256, 0, stream>>>(Ag, Wr_b, br, read_w);
    k2_read_vec<<<4096, 256, 0, stream>>>(mem, read_w, Ag, Aout);
    k3_gates_mfma<<<dim3(64, 4), 256, 0, stream>>>(Ag, Wg, bsum, c, h_new, c_new, Aout);
    k4_heads<<<64, 256, 0, stream>>>(Aout, Wh_b, bh_b, write_w, erase, addv);
    k6_out<<<64, 256, 0, stream>>>(Aout, Wo_b, bo, out);
    k5_mem_update<<<4096, 256, 0, stream>>>(mem, write_w, erase, addv, mem_new);
}

// Round 3
// 110.555 us; speedup vs baseline: 3.0182x; 1.1258x over previous
//
#include <hip/hip_runtime.h>
#include <math.h>

// Shapes: B=4096, N=128, D=64, H=256, O=128
// d_out (floats): out[B*128] | mem_new[B*128*64] | h_new[B*256] | c_new[B*256]
// ws: read_w f32 | write_w f32 | erase f32 | addv f32 | bsum f32 | bh_b f32 | bf16 region:
//     Ag[4096][448]=[x|rv|h], Aout[4096][320]=[h_new|rv], Wg[1024][448], Wr_b[128][256],
//     Wh_b[256][256], Wo_b[128][320]

typedef __attribute__((ext_vector_type(8))) short bf16x8;
typedef __attribute__((ext_vector_type(4))) float f32x4;
typedef __attribute__((ext_vector_type(4))) unsigned short us4;

#define MFMA16(a, b, c) __builtin_amdgcn_mfma_f32_16x16x32_bf16(a, b, c, 0, 0, 0)
#define GLL16(gp, lp) __builtin_amdgcn_global_load_lds( \
    (const __attribute__((address_space(1))) void*)(gp), \
    (__attribute__((address_space(3))) void*)(lp), 16, 0, 0)
#define SW(row, s) ((s) ^ ((row) & 3))

__device__ __forceinline__ float sigf(float v) { return 1.f / (1.f + __expf(-v)); }

__device__ __forceinline__ unsigned short f2bf(float f) {
    unsigned u = __builtin_bit_cast(unsigned, f);
    u = (u + 0x7FFFu + ((u >> 16) & 1u)) >> 16;
    return (unsigned short)u;
}

// ---------------- P: pack all weights + activations to bf16 ----------------
__global__ __launch_bounds__(256) void p_pack(
    const float* __restrict__ Wih, const float* __restrict__ Whh,
    const float* __restrict__ bih, const float* __restrict__ bhh,
    const float* __restrict__ Wr, const float* __restrict__ Ww,
    const float* __restrict__ We, const float* __restrict__ Wa,
    const float* __restrict__ bw, const float* __restrict__ be,
    const float* __restrict__ ba, const float* __restrict__ Wo,
    const float* __restrict__ x, const float* __restrict__ h,
    unsigned short* __restrict__ Wg, float* __restrict__ bsum,
    unsigned short* __restrict__ Wr_b, unsigned short* __restrict__ Wh_b,
    float* __restrict__ bh_b, unsigned short* __restrict__ Wo_b,
    unsigned short* __restrict__ Ag)
{
    int idx = blockIdx.x * 256 + threadIdx.x;
    int stride = gridDim.x * 256;
    for (int i = idx; i < 1024 * 448; i += stride) {
        int r = i / 448, cc = i - r * 448;
        float v = (cc < 192) ? Wih[(size_t)r * 192 + cc] : Whh[(size_t)r * 256 + (cc - 192)];
        Wg[i] = f2bf(v);
    }
    for (int i = idx; i < 1024; i += stride) bsum[i] = bih[i] + bhh[i];
    for (int i = idx; i < 128 * 256; i += stride) Wr_b[i] = f2bf(Wr[i]);
    for (int i = idx; i < 256 * 256; i += stride) {
        int r = i >> 8, cc = i & 255;
        float v = (r < 128) ? Ww[(size_t)r * 256 + cc]
                : (r < 192) ? We[(size_t)(r - 128) * 256 + cc]
                            : Wa[(size_t)(r - 192) * 256 + cc];
        Wh_b[i] = f2bf(v);
    }
    for (int i = idx; i < 256; i += stride)
        bh_b[i] = (i < 128) ? bw[i] : (i < 192 ? be[i - 128] : ba[i - 192]);
    for (int i = idx; i < 128 * 320; i += stride) Wo_b[i] = f2bf(Wo[i]);
    // pack x,h into Ag rows [x(128) | rv(64, later) | h(256)]
    for (int i = idx; i < 4096 * 96; i += stride) {
        int row = i / 96, j = i - row * 96;
        float4 v = (j < 32) ? ((const float4*)(x + (size_t)row * 128))[j]
                            : ((const float4*)(h + (size_t)row * 256))[j - 32];
        us4 o = { f2bf(v.x), f2bf(v.y), f2bf(v.z), f2bf(v.w) };
        int col = (j < 32) ? j * 4 : 192 + (j - 32) * 4;
        *(us4*)(Ag + (size_t)row * 448 + col) = o;
    }
}

// ---------------- K1: read_w = softmax(h @ Wr^T + br) [MFMA] ----------------
// grid 128 (32 rows/block), block 128 (2 waves). Wave = 16 rows, all 128 cols. K=256.
__global__ __launch_bounds__(128) void k1_read_attn(
    const unsigned short* __restrict__ Ag, const unsigned short* __restrict__ Wr_b,
    const float* __restrict__ br, float* __restrict__ read_w)
{
    __shared__ unsigned short As[32 * 32];
    __shared__ unsigned short Bs[128 * 32];
    int t = threadIdx.x;
    int wid = t >> 6, lane = t & 63;
    int cl = lane & 15, ks = lane >> 4;
    int b0 = blockIdx.x * 32;

    int arow = t >> 2;
    const unsigned short* aSrc = Ag + (size_t)(b0 + arow) * 448 + 192 + SW(arow, t & 3) * 8;
    unsigned short* aDst = As + wid * 512;
    const unsigned short* bSrc[4];
    unsigned short* bDst[4];
#pragma unroll
    for (int J = 0; J < 4; ++J) {
        int rJ = J * 32 + (t >> 2);
        bSrc[J] = Wr_b + (size_t)rJ * 256 + SW(rJ, t & 3) * 8;
        bDst[J] = Bs + J * 1024 + wid * 512;
    }

    int mr = wid * 16 + cl;
    int aOff = mr * 32 + SW(mr, ks) * 8;
    int bOff[8];
#pragma unroll
    for (int f = 0; f < 8; ++f) { int br_ = f * 16 + cl; bOff[f] = br_ * 32 + SW(br_, ks) * 8; }

    f32x4 acc[8] = {};
    for (int kc = 0; kc < 8; ++kc) {
        __syncthreads();
        GLL16(aSrc, aDst);
#pragma unroll
        for (int J = 0; J < 4; ++J) GLL16(bSrc[J], bDst[J]);
        aSrc += 32;
#pragma unroll
        for (int J = 0; J < 4; ++J) bSrc[J] += 32;
        __syncthreads();
        bf16x8 a = *(const bf16x8*)(As + aOff);
#pragma unroll
        for (int f = 0; f < 8; ++f)
            acc[f] = MFMA16(a, *(const bf16x8*)(Bs + bOff[f]), acc[f]);
    }

    float bb[8];
#pragma unroll
    for (int f = 0; f < 8; ++f) bb[f] = br[f * 16 + cl];
#pragma unroll
    for (int r = 0; r < 4; ++r) {
        int row = b0 + wid * 16 + ks * 4 + r;
        float v[8];
#pragma unroll
        for (int f = 0; f < 8; ++f) v[f] = acc[f][r] + bb[f];
        float m = v[0];
#pragma unroll
        for (int f = 1; f < 8; ++f) m = fmaxf(m, v[f]);
#pragma unroll
        for (int mk = 8; mk >= 1; mk >>= 1) m = fmaxf(m, __shfl_xor(m, mk));
        float s = 0.f;
#pragma unroll
        for (int f = 0; f < 8; ++f) { v[f] = __expf(v[f] - m); s += v[f]; }
#pragma unroll
        for (int mk = 8; mk >= 1; mk >>= 1) s += __shfl_xor(s, mk);
        float inv = 1.f / s;
#pragma unroll
        for (int f = 0; f < 8; ++f)
            read_w[(size_t)row * 128 + f * 16 + cl] = v[f] * inv;
    }
}

// ---------------- K2: read_vec (streaming) -> bf16 into Ag & Aout ----------------
__global__ __launch_bounds__(256) void k2_read_vec(
    const float* __restrict__ mem, const float* __restrict__ read_w,
    unsigned short* __restrict__ Ag, unsigned short* __restrict__ Aout)
{
    __shared__ float part[16][68];
    int t = threadIdx.x;
    int b = blockIdx.x;
    int np = t >> 4, d4 = t & 15;
    const float4* m4 = (const float4*)(mem + (size_t)b * 8192);
    float4 acc = make_float4(0.f, 0.f, 0.f, 0.f);
#pragma unroll
    for (int j = 0; j < 8; ++j) {
        int n = np + 16 * j;
        float w = read_w[(size_t)b * 128 + n];
        float4 mv = m4[t + 256 * j];
        acc.x += w * mv.x; acc.y += w * mv.y; acc.z += w * mv.z; acc.w += w * mv.w;
    }
    part[np][d4 * 4 + 0] = acc.x; part[np][d4 * 4 + 1] = acc.y;
    part[np][d4 * 4 + 2] = acc.z; part[np][d4 * 4 + 3] = acc.w;
    __syncthreads();
    if (t < 64) {
        float s = 0.f;
#pragma unroll
        for (int q = 0; q < 16; ++q) s += part[q][t];
        unsigned short bv = f2bf(s);
        Ag[(size_t)b * 448 + 128 + t] = bv;
        Aout[(size_t)b * 320 + 256 + t] = bv;
    }
}

// ---------------- K3: gates GEMM [MFMA] + LSTM pointwise ----------------
// grid (64,4), block 256. Block: 64 rows x 64 units x 4 gates. K=448.
// Wave w: ALL 4 row-frags x units [u0+w*16, +16) x all 4 gates -> 4x4 outer product:
// 8 ds_read_b128 per 16 MFMA per K-chunk.
__global__ __launch_bounds__(256) void k3_gates_mfma(
    const unsigned short* __restrict__ Ag, const unsigned short* __restrict__ Wg,
    const float* __restrict__ bsum, const float* __restrict__ c,
    float* __restrict__ h_new, float* __restrict__ c_new,
    unsigned short* __restrict__ Aout)
{
    __shared__ unsigned short As[64 * 32];
    __shared__ unsigned short Bs[256 * 32];
    int t = threadIdx.x;
    int wid = t >> 6, lane = t & 63;
    int cl = lane & 15, ks = lane >> 4;
    int b0 = blockIdx.x * 64;
    int u0 = blockIdx.y * 64;

    int arow = t >> 2;
    const unsigned short* aSrc = Ag + (size_t)(b0 + arow) * 448 + SW(arow, t & 3) * 8;
    unsigned short* aDst = As + wid * 512;
    const unsigned short* bSrc[4];
    unsigned short* bDst[4];
#pragma unroll
    for (int j = 0; j < 4; ++j) {
        int i = j * 256 + t;
        int rl = i >> 2;                    // 0..255
        int g = rl >> 6, u = rl & 63;
        bSrc[j] = Wg + (size_t)(g * 256 + u0 + u) * 448 + SW(rl, t & 3) * 8;
        bDst[j] = Bs + (j * 256 + wid * 64) * 8;
    }

    int aOff[4];
#pragma unroll
    for (int rf = 0; rf < 4; ++rf) {
        int mr = rf * 16 + cl;
        aOff[rf] = mr * 32 + SW(mr, ks) * 8;
    }
    int bOff[4];
#pragma unroll
    for (int g = 0; g < 4; ++g) {
        int br_ = g * 64 + wid * 16 + cl;
        bOff[g] = br_ * 32 + SW(br_, ks) * 8;
    }

    f32x4 acc[4][4] = {};  // [rf][g]
    for (int kc = 0; kc < 14; ++kc) {
        __syncthreads();
        GLL16(aSrc, aDst);
        GLL16(bSrc[0], bDst[0]); GLL16(bSrc[1], bDst[1]);
        GLL16(bSrc[2], bDst[2]); GLL16(bSrc[3], bDst[3]);
        aSrc += 32;
#pragma unroll
        for (int j = 0; j < 4; ++j) bSrc[j] += 32;
        __syncthreads();
        bf16x8 a[4], b[4];
#pragma unroll
        for (int rf = 0; rf < 4; ++rf) a[rf] = *(const bf16x8*)(As + aOff[rf]);
#pragma unroll
        for (int g = 0; g < 4; ++g) b[g] = *(const bf16x8*)(Bs + bOff[g]);
#pragma unroll
        for (int rf = 0; rf < 4; ++rf)
#pragma unroll
            for (int g = 0; g < 4; ++g)
                acc[rf][g] = MFMA16(a[rf], b[g], acc[rf][g]);
    }

    int unit = u0 + wid * 16 + cl;
    float bi = bsum[unit], bf_ = bsum[256 + unit];
    float bg = bsum[512 + unit], bo_ = bsum[768 + unit];
#pragma unroll
    for (int rf = 0; rf < 4; ++rf) {
#pragma unroll
        for (int r = 0; r < 4; ++r) {
            int row = b0 + rf * 16 + ks * 4 + r;
            float iv = sigf(acc[rf][0][r] + bi);
            float fv = sigf(acc[rf][1][r] + bf_);
            float gv = tanhf(acc[rf][2][r] + bg);
            float ov = sigf(acc[rf][3][r] + bo_);
            float cv = fv * c[(size_t)row * 256 + unit] + iv * gv;
            float hv = ov * tanhf(cv);
            c_new[(size_t)row * 256 + unit] = cv;
            h_new[(size_t)row * 256 + unit] = hv;
            Aout[(size_t)row * 320 + unit] = f2bf(hv);
        }
    }
}

// ---------------- K46: heads (K=256) + out (K=320) fused, from Aout ----------------
// grid 128 (32 rows/block), block 256 (4 waves). Wave (rf=wid>>1, ch=wid&1):
// heads frags ch*8..+8 (ch0: all 128 write cols -> in-wave softmax; ch1: erase|add),
// out frags ch*4..+4.
__global__ __launch_bounds__(256) void k46_heads_out(
    const unsigned short* __restrict__ Aout, const unsigned short* __restrict__ Wh_b,
    const unsigned short* __restrict__ Wo_b, const float* __restrict__ bh_b,
    const float* __restrict__ bo, float* __restrict__ write_w,
    float* __restrict__ erase, float* __restrict__ addv, float* __restrict__ outp)
{
    __shared__ unsigned short As[32 * 32];
    __shared__ unsigned short Bh[256 * 32];
    __shared__ unsigned short Bo[128 * 32];
    int t = threadIdx.x;
    int wid = t >> 6, lane = t & 63;
    int cl = lane & 15, ks = lane >> 4;
    int rf = wid >> 1, ch = wid & 1;
    int b0 = blockIdx.x * 32;

    int arow = t >> 2;  // 0..63, but A tile has 32 rows: only t<128 stages
    const unsigned short* aSrc = Aout + (size_t)(b0 + (arow & 31)) * 320 + SW(arow & 31, t & 3) * 8;
    unsigned short* aDst = As + (wid & 1) * 512;
    const unsigned short* bhSrc[4];
    unsigned short* bhDst[4];
#pragma unroll
    for (int j = 0; j < 4; ++j) {
        int rl = (j * 256 + t) >> 2;        // 0..255
        bhSrc[j] = Wh_b + (size_t)rl * 256 + SW(rl, t & 3) * 8;
        bhDst[j] = Bh + (j * 256 + wid * 64) * 8;
    }
    const unsigned short* boSrc[2];
    unsigned short* boDst[2];
#pragma unroll
    for (int j = 0; j < 2; ++j) {
        int rj = j * 64 + (t >> 2);         // 0..127
        boSrc[j] = Wo_b + (size_t)rj * 320 + SW(rj, t & 3) * 8;
        boDst[j] = Bo + j * 2048 + wid * 512;
    }

    int mr = rf * 16 + cl;
    int aOff = mr * 32 + SW(mr, ks) * 8;
    int bOffH[8], bOffO[4];
#pragma unroll
    for (int f = 0; f < 8; ++f) { int br_ = (ch * 8 + f) * 16 + cl; bOffH[f] = br_ * 32 + SW(br_, ks) * 8; }
#pragma unroll
    for (int f = 0; f < 4; ++f) { int br_ = (ch * 4 + f) * 16 + cl; bOffO[f] = br_ * 32 + SW(br_, ks) * 8; }

    f32x4 accH[8] = {};
    f32x4 accO[4] = {};
    for (int kc = 0; kc < 10; ++kc) {
        __syncthreads();
        if (t < 128) GLL16(aSrc, aDst);
        if (kc < 8) {
            GLL16(bhSrc[0], bhDst[0]); GLL16(bhSrc[1], bhDst[1]);
            GLL16(bhSrc[2], bhDst[2]); GLL16(bhSrc[3], bhDst[3]);
        }
        GLL16(boSrc[0], boDst[0]); GLL16(boSrc[1], boDst[1]);
        aSrc += 32;
#pragma unroll
        for (int j = 0; j < 4; ++j) bhSrc[j] += 32;
#pragma unroll
        for (int j = 0; j < 2; ++j) boSrc[j] += 32;
        __syncthreads();
        bf16x8 a = *(const bf16x8*)(As + aOff);
        if (kc < 8) {
#pragma unroll
            for (int f = 0; f < 8; ++f)
                accH[f] = MFMA16(a, *(const bf16x8*)(Bh + bOffH[f]), accH[f]);
        }
#pragma unroll
        for (int f = 0; f < 4; ++f)
            accO[f] = MFMA16(a, *(const bf16x8*)(Bo + bOffO[f]), accO[f]);
    }

    float bbh[8], bbo[4];
#pragma unroll
    for (int f = 0; f < 8; ++f) bbh[f] = bh_b[(ch * 8 + f) * 16 + cl];
#pragma unroll
    for (int f = 0; f < 4; ++f) bbo[f] = bo[ch * 64 + f * 16 + cl];

#pragma unroll
    for (int r = 0; r < 4; ++r) {
        int row = b0 + rf * 16 + ks * 4 + r;
        if (ch == 0) {
            float v[8];
#pragma unroll
            for (int f = 0; f < 8; ++f) v[f] = accH[f][r] + bbh[f];
            float m = v[0];
#pragma unroll
            for (int f = 1; f < 8; ++f) m = fmaxf(m, v[f]);
#pragma unroll
            for (int mk = 8; mk >= 1; mk >>= 1) m = fmaxf(m, __shfl_xor(m, mk));
            float s = 0.f;
#pragma unroll
            for (int f = 0; f < 8; ++f) { v[f] = __expf(v[f] - m); s += v[f]; }
#pragma unroll
            for (int mk = 8; mk >= 1; mk >>= 1) s += __shfl_xor(s, mk);
            float inv = 1.f / s;
#pragma unroll
            for (int f = 0; f < 8; ++f)
                write_w[(size_t)row * 128 + f * 16 + cl] = v[f] * inv;
        } else {
#pragma unroll
            for (int f = 0; f < 4; ++f)
                erase[(size_t)row * 64 + f * 16 + cl] = sigf(accH[f][r] + bbh[f]);
#pragma unroll
            for (int f = 4; f < 8; ++f)
                addv[(size_t)row * 64 + (f - 4) * 16 + cl] = tanhf(accH[f][r] + bbh[f]);
        }
#pragma unroll
        for (int f = 0; f < 4; ++f)
            outp[(size_t)row * 128 + ch * 64 + f * 16 + cl] = accO[f][r] + bbo[f];
    }
}

// ---------------- K5: mem_new = memory*(1 - ww*erase) + ww*add ----------------
__global__ __launch_bounds__(256) void k5_mem_update(
    const float* __restrict__ mem, const float* __restrict__ write_w,
    const float* __restrict__ erase, const float* __restrict__ addv,
    float* __restrict__ mem_new)
{
    int t = threadIdx.x; int b = blockIdx.x;
    int np = t >> 4, d0 = (t & 15) * 4;
    const f32x4* m4 = (const f32x4*)(mem + (size_t)b * 8192);
    f32x4* o4 = (f32x4*)(mem_new + (size_t)b * 8192);
    f32x4 e4 = *(const f32x4*)(erase + (size_t)b * 64 + d0);
    f32x4 a4 = *(const f32x4*)(addv + (size_t)b * 64 + d0);
#pragma unroll
    for (int j = 0; j < 8; ++j) {
        int n = np + 16 * j;
        float w = write_w[(size_t)b * 128 + n];
        f32x4 m = m4[t + 256 * j];
        f32x4 r;
        r[0] = m[0] * (1.f - w * e4[0]) + w * a4[0];
        r[1] = m[1] * (1.f - w * e4[1]) + w * a4[1];
        r[2] = m[2] * (1.f - w * e4[2]) + w * a4[2];
        r[3] = m[3] * (1.f - w * e4[3]) + w * a4[3];
        __builtin_nontemporal_store(r, &o4[t + 256 * j]);
    }
}

extern "C" void kernel_launch(void* const* d_in, const int* in_sizes, int n_in,
                              void* d_out, int out_size, void* d_ws, size_t ws_size,
                              hipStream_t stream)
{
    const float* x    = (const float*)d_in[0];
    const float* mem  = (const float*)d_in[1];
    const float* h    = (const float*)d_in[2];
    const float* c    = (const float*)d_in[3];
    const float* Wih  = (const float*)d_in[4];
    const float* Whh  = (const float*)d_in[5];
    const float* bih  = (const float*)d_in[6];
    const float* bhh  = (const float*)d_in[7];
    const float* Wr   = (const float*)d_in[8];
    const float* br   = (const float*)d_in[9];
    const float* Ww   = (const float*)d_in[10];
    const float* bw   = (const float*)d_in[11];
    const float* We   = (const float*)d_in[12];
    const float* be   = (const float*)d_in[13];
    const float* Wa   = (const float*)d_in[14];
    const float* ba   = (const float*)d_in[15];
    const float* Wo   = (const float*)d_in[16];
    const float* bo   = (const float*)d_in[17];

    float* out     = (float*)d_out;
    float* mem_new = out + 524288;
    float* h_new   = out + 34078720;
    float* c_new   = out + 35127296;

    float* ws      = (float*)d_ws;
    float* read_w  = ws;                       // 4096*128
    float* write_w = ws + 524288;              // 4096*128
    float* erase   = ws + 1048576;             // 4096*64
    float* addv    = ws + 1310720;             // 4096*64
    float* bsum    = ws + 1572864;             // 1024
    float* bh_b    = ws + 1573888;             // 256
    unsigned short* ub   = (unsigned short*)(ws + 1574144);
    unsigned short* Ag   = ub;                 // 4096*448
    unsigned short* Aout = ub + 1835008;       // 4096*320
    unsigned short* Wg   = ub + 3145728;       // 1024*448
    unsigned short* Wr_b = ub + 3604480;       // 128*256
    unsigned short* Wh_b = ub + 3637248;       // 256*256
    unsigned short* Wo_b = ub + 3702784;       // 128*320

    p_pack<<<512, 256, 0, stream>>>(Wih, Whh, bih, bhh, Wr, Ww, We, Wa, bw, be, ba, Wo,
                                    x, h, Wg, bsum, Wr_b, Wh_b, bh_b, Wo_b, Ag);
    k1_read_attn<<<128, 128, 0, stream>>>(Ag, Wr_b, br, read_w);
    k2_read_vec<<<4096, 256, 0, stream>>>(mem, read_w, Ag, Aout);
    k3_gates_mfma<<<dim3(64, 4), 256, 0, stream>>>(Ag, Wg, bsum, c, h_new, c_new, Aout);
    k46_heads_out<<<128, 256, 0, stream>>>(Aout, Wh_b, Wo_b, bh_b, bo,
                                           write_w, erase, addv, out);
    k5_mem_update<<<4096, 256, 0, stream>>>(mem, write_w, erase, addv, mem_new);
}

// Round 4
// 106.636 us; speedup vs baseline: 3.1291x; 1.0368x over previous
//
#include <hip/hip_runtime.h>
#include <math.h>

// Shapes: B=4096, N=128, D=64, H=256, O=128
// d_out (floats): out[B*128] | mem_new[B*128*64] | h_new[B*256] | c_new[B*256]
// ws: bsum f32[1024] | bh_b f32[256] | bf16 region:
//     Ag[4096][448]=[x|rv|h], Aout[4096][320]=[h_new|rv], Wg[1024][448],
//     Wh_b[256][256], Wo_b[128][320]

typedef __attribute__((ext_vector_type(8))) short bf16x8;
typedef __attribute__((ext_vector_type(4))) float f32x4;
typedef __attribute__((ext_vector_type(4))) unsigned short us4;

#define MFMA16(a, b, c) __builtin_amdgcn_mfma_f32_16x16x32_bf16(a, b, c, 0, 0, 0)
#define GLL16(gp, lp) __builtin_amdgcn_global_load_lds( \
    (const __attribute__((address_space(1))) void*)(gp), \
    (__attribute__((address_space(3))) void*)(lp), 16, 0, 0)
#define SW(row, s) ((s) ^ ((row) & 3))

__device__ __forceinline__ float sigf(float v) { return 1.f / (1.f + __expf(-v)); }

__device__ __forceinline__ unsigned short f2bf(float f) {
    unsigned u = __builtin_bit_cast(unsigned, f);
    u = (u + 0x7FFFu + ((u >> 16) & 1u)) >> 16;
    return (unsigned short)u;
}

// =============== kA: pack + read-attn + read_vec streaming ===============
// grid 256 (16 rows/block), block 256 (4 waves).
__global__ __launch_bounds__(256) void kA_prep(
    const float* __restrict__ Wih, const float* __restrict__ Whh,
    const float* __restrict__ bih, const float* __restrict__ bhh,
    const float* __restrict__ Wr, const float* __restrict__ br,
    const float* __restrict__ Ww, const float* __restrict__ We,
    const float* __restrict__ Wa, const float* __restrict__ bw,
    const float* __restrict__ be, const float* __restrict__ ba,
    const float* __restrict__ Wo, const float* __restrict__ x,
    const float* __restrict__ h, const float* __restrict__ mem,
    unsigned short* __restrict__ Wg, float* __restrict__ bsum,
    unsigned short* __restrict__ Wh_b, float* __restrict__ bh_b,
    unsigned short* __restrict__ Wo_b, unsigned short* __restrict__ Ag,
    unsigned short* __restrict__ Aout)
{
    __shared__ unsigned short As[16 * 32];
    __shared__ unsigned short Bs[128 * 32];
    __shared__ float sc[16][128];
    __shared__ float wL[16][128];
    __shared__ float part[16][68];

    int t = threadIdx.x;
    int wid = t >> 6, lane = t & 63;
    int cl = lane & 15, ks = lane >> 4;
    int b0 = blockIdx.x * 16;

    // ---- phase 0: pack weights + x,h (striped across all blocks) ----
    int idx = blockIdx.x * 256 + t;
    int stride = gridDim.x * 256;
    for (int i = idx; i < 1024 * 448; i += stride) {
        int r = i / 448, cc = i - r * 448;
        float v = (cc < 192) ? Wih[(size_t)r * 192 + cc] : Whh[(size_t)r * 256 + (cc - 192)];
        Wg[i] = f2bf(v);
    }
    for (int i = idx; i < 1024; i += stride) bsum[i] = bih[i] + bhh[i];
    for (int i = idx; i < 256 * 256; i += stride) {
        int r = i >> 8, cc = i & 255;
        float v = (r < 128) ? Ww[(size_t)r * 256 + cc]
                : (r < 192) ? We[(size_t)(r - 128) * 256 + cc]
                            : Wa[(size_t)(r - 192) * 256 + cc];
        Wh_b[i] = f2bf(v);
    }
    for (int i = idx; i < 256; i += stride)
        bh_b[i] = (i < 128) ? bw[i] : (i < 192 ? be[i - 128] : ba[i - 192]);
    for (int i = idx; i < 128 * 320; i += stride) Wo_b[i] = f2bf(Wo[i]);
    for (int i = idx; i < 4096 * 96; i += stride) {
        int row = i / 96, j = i - row * 96;
        float4 v = (j < 32) ? ((const float4*)(x + (size_t)row * 128))[j]
                            : ((const float4*)(h + (size_t)row * 256))[j - 32];
        us4 o = { f2bf(v.x), f2bf(v.y), f2bf(v.z), f2bf(v.w) };
        int col = (j < 32) ? j * 4 : 192 + (j - 32) * 4;
        *(us4*)(Ag + (size_t)row * 448 + col) = o;
    }

    // ---- phase 1: scores = h @ Wr^T  (16 rows x 128 cols, K=256) ----
    int aOff = cl * 32 + SW(cl, ks) * 8;
    int bOff[4];
#pragma unroll
    for (int f = 0; f < 4; ++f) {
        int br_ = (wid * 4 + f) * 16 + cl;
        bOff[f] = br_ * 32 + SW(br_, ks) * 8;
    }
    f32x4 acc[4] = {};
    for (int kc = 0; kc < 8; ++kc) {
        __syncthreads();
        {   // h tile: 16 rows x 32 k -> bf16 LDS (swizzled)
            int row = t >> 4, k0 = (t & 15) * 2;
            float2 hv = *(const float2*)(h + (size_t)(b0 + row) * 256 + kc * 32 + k0);
            unsigned pk = (unsigned)f2bf(hv.x) | ((unsigned)f2bf(hv.y) << 16);
            *(unsigned*)(As + row * 32 + SW(row, k0 >> 3) * 8 + (k0 & 7)) = pk;
        }
        {   // Wr tile: 128 rows x 32 k
            int row = t >> 1, k0 = (t & 1) * 16;
            const float4* wp = (const float4*)(Wr + (size_t)row * 256 + kc * 32 + k0);
            float4 w0 = wp[0], w1 = wp[1], w2 = wp[2], w3 = wp[3];
            us4 p0 = { f2bf(w0.x), f2bf(w0.y), f2bf(w0.z), f2bf(w0.w) };
            us4 p1 = { f2bf(w1.x), f2bf(w1.y), f2bf(w1.z), f2bf(w1.w) };
            us4 p2 = { f2bf(w2.x), f2bf(w2.y), f2bf(w2.z), f2bf(w2.w) };
            us4 p3 = { f2bf(w3.x), f2bf(w3.y), f2bf(w3.z), f2bf(w3.w) };
            int g0 = k0 >> 3;
            unsigned short* basep = Bs + row * 32;
            *(us4*)(basep + SW(row, g0) * 8)     = p0;
            *(us4*)(basep + SW(row, g0) * 8 + 4) = p1;
            *(us4*)(basep + SW(row, g0 + 1) * 8)     = p2;
            *(us4*)(basep + SW(row, g0 + 1) * 8 + 4) = p3;
        }
        __syncthreads();
        if (wid < 2) {
            bf16x8 a = *(const bf16x8*)(As + aOff);
#pragma unroll
            for (int f = 0; f < 4; ++f)
                acc[f] = MFMA16(a, *(const bf16x8*)(Bs + bOff[f]), acc[f]);
        }
    }
    if (wid < 2) {
#pragma unroll
        for (int f = 0; f < 4; ++f)
#pragma unroll
            for (int r = 0; r < 4; ++r)
                sc[ks * 4 + r][(wid * 4 + f) * 16 + cl] = acc[f][r];
    }
    __syncthreads();
    {   // softmax: 16 threads per row, 8 cols each
        int row = t >> 4, l = t & 15;
        float v[8];
#pragma unroll
        for (int j = 0; j < 8; ++j) v[j] = sc[row][l + 16 * j] + br[l + 16 * j];
        float m = v[0];
#pragma unroll
        for (int j = 1; j < 8; ++j) m = fmaxf(m, v[j]);
#pragma unroll
        for (int mk = 8; mk >= 1; mk >>= 1) m = fmaxf(m, __shfl_xor(m, mk));
        float s = 0.f;
#pragma unroll
        for (int j = 0; j < 8; ++j) { v[j] = __expf(v[j] - m); s += v[j]; }
#pragma unroll
        for (int mk = 8; mk >= 1; mk >>= 1) s += __shfl_xor(s, mk);
        float inv = 1.f / s;
#pragma unroll
        for (int j = 0; j < 8; ++j) wL[row][l + 16 * j] = v[j] * inv;
    }
    __syncthreads();

    // ---- phase 2: stream 16 memory rows, weighted-sum -> rv ----
    int np = t >> 4, d4 = t & 15;
    for (int r = 0; r < 16; ++r) {
        int row = b0 + r;
        const f32x4* m4 = (const f32x4*)(mem + (size_t)row * 8192);
        f32x4 a4 = { 0.f, 0.f, 0.f, 0.f };
#pragma unroll
        for (int j = 0; j < 8; ++j) {
            float w = wL[r][np + 16 * j];
            f32x4 mv = m4[t + 256 * j];
            a4 += w * mv;
        }
        part[np][d4 * 4 + 0] = a4[0]; part[np][d4 * 4 + 1] = a4[1];
        part[np][d4 * 4 + 2] = a4[2]; part[np][d4 * 4 + 3] = a4[3];
        __syncthreads();
        if (t < 64) {
            float s = 0.f;
#pragma unroll
            for (int q = 0; q < 16; ++q) s += part[q][t];
            unsigned short bv = f2bf(s);
            Ag[(size_t)row * 448 + 128 + t] = bv;
            Aout[(size_t)row * 320 + 256 + t] = bv;
        }
        __syncthreads();
    }
}

// =============== kB: gates GEMM [MFMA] + LSTM pointwise ===============
// grid (64,4), block 256. Block: 64 rows x 64 units x 4 gates. K=448.
__global__ __launch_bounds__(256) void kB_gates(
    const unsigned short* __restrict__ Ag, const unsigned short* __restrict__ Wg,
    const float* __restrict__ bsum, const float* __restrict__ c,
    float* __restrict__ h_new, float* __restrict__ c_new,
    unsigned short* __restrict__ Aout)
{
    __shared__ unsigned short As[64 * 32];
    __shared__ unsigned short Bs[256 * 32];
    int t = threadIdx.x;
    int wid = t >> 6, lane = t & 63;
    int cl = lane & 15, ks = lane >> 4;
    int b0 = blockIdx.x * 64;
    int u0 = blockIdx.y * 64;

    int arow = t >> 2;
    const unsigned short* aSrc = Ag + (size_t)(b0 + arow) * 448 + SW(arow, t & 3) * 8;
    unsigned short* aDst = As + wid * 512;
    const unsigned short* bSrc[4];
    unsigned short* bDst[4];
#pragma unroll
    for (int j = 0; j < 4; ++j) {
        int rl = (j * 256 + t) >> 2;
        int g = rl >> 6, u = rl & 63;
        bSrc[j] = Wg + (size_t)(g * 256 + u0 + u) * 448 + SW(rl, t & 3) * 8;
        bDst[j] = Bs + (j * 256 + wid * 64) * 8;
    }

    int aOff[4];
#pragma unroll
    for (int rf = 0; rf < 4; ++rf) {
        int mr = rf * 16 + cl;
        aOff[rf] = mr * 32 + SW(mr, ks) * 8;
    }
    int bOff[4];
#pragma unroll
    for (int g = 0; g < 4; ++g) {
        int br_ = g * 64 + wid * 16 + cl;
        bOff[g] = br_ * 32 + SW(br_, ks) * 8;
    }

    f32x4 acc[4][4] = {};  // [rf][g]
    for (int kc = 0; kc < 14; ++kc) {
        __syncthreads();
        GLL16(aSrc, aDst);
        GLL16(bSrc[0], bDst[0]); GLL16(bSrc[1], bDst[1]);
        GLL16(bSrc[2], bDst[2]); GLL16(bSrc[3], bDst[3]);
        aSrc += 32;
#pragma unroll
        for (int j = 0; j < 4; ++j) bSrc[j] += 32;
        __syncthreads();
        bf16x8 a[4], b[4];
#pragma unroll
        for (int rf = 0; rf < 4; ++rf) a[rf] = *(const bf16x8*)(As + aOff[rf]);
#pragma unroll
        for (int g = 0; g < 4; ++g) b[g] = *(const bf16x8*)(Bs + bOff[g]);
#pragma unroll
        for (int rf = 0; rf < 4; ++rf)
#pragma unroll
            for (int g = 0; g < 4; ++g)
                acc[rf][g] = MFMA16(a[rf], b[g], acc[rf][g]);
    }

    int unit = u0 + wid * 16 + cl;
    float bi = bsum[unit], bf_ = bsum[256 + unit];
    float bg = bsum[512 + unit], bo_ = bsum[768 + unit];
#pragma unroll
    for (int rf = 0; rf < 4; ++rf) {
#pragma unroll
        for (int r = 0; r < 4; ++r) {
            int row = b0 + rf * 16 + ks * 4 + r;
            float iv = sigf(acc[rf][0][r] + bi);
            float fv = sigf(acc[rf][1][r] + bf_);
            float gv = tanhf(acc[rf][2][r] + bg);
            float ov = sigf(acc[rf][3][r] + bo_);
            float cv = fv * c[(size_t)row * 256 + unit] + iv * gv;
            float hv = ov * tanhf(cv);
            c_new[(size_t)row * 256 + unit] = cv;
            h_new[(size_t)row * 256 + unit] = hv;
            Aout[(size_t)row * 320 + unit] = f2bf(hv);
        }
    }
}

// =============== kC: heads + out GEMM + mem update ===============
// grid 256 (16 rows/block), block 256 (4 waves).
__global__ __launch_bounds__(256) void kC_heads_out_mem(
    const unsigned short* __restrict__ Aout, const unsigned short* __restrict__ Wh_b,
    const unsigned short* __restrict__ Wo_b, const float* __restrict__ bh_b,
    const float* __restrict__ bo, const float* __restrict__ mem,
    float* __restrict__ outp, float* __restrict__ mem_new)
{
    __shared__ unsigned short As[16 * 32];
    __shared__ unsigned short Bh[256 * 32];
    __shared__ unsigned short Bo[128 * 32];
    __shared__ float sc[16][256];
    __shared__ __align__(16) float wL[16][128];
    __shared__ __align__(16) float eL[16][64];
    __shared__ __align__(16) float aL[16][64];

    int t = threadIdx.x;
    int wid = t >> 6, lane = t & 63;
    int cl = lane & 15, ks = lane >> 4;
    int b0 = blockIdx.x * 16;

    const unsigned short* aSrc = Aout + (size_t)(b0 + (lane >> 2)) * 320 + SW(lane >> 2, lane & 3) * 8;
    const unsigned short* bhSrc[4];
    unsigned short* bhDst[4];
#pragma unroll
    for (int j = 0; j < 4; ++j) {
        int rl = (j * 256 + t) >> 2;
        bhSrc[j] = Wh_b + (size_t)rl * 256 + SW(rl, t & 3) * 8;
        bhDst[j] = Bh + (j * 256 + wid * 64) * 8;
    }
    const unsigned short* boSrc[2];
    unsigned short* boDst[2];
#pragma unroll
    for (int j = 0; j < 2; ++j) {
        int rj = j * 64 + (t >> 2);
        boSrc[j] = Wo_b + (size_t)rj * 320 + SW(rj, t & 3) * 8;
        boDst[j] = Bo + j * 2048 + wid * 512;
    }

    int aOff = cl * 32 + SW(cl, ks) * 8;
    int bOffH[4], bOffO[2];
#pragma unroll
    for (int f = 0; f < 4; ++f) { int br_ = (wid * 4 + f) * 16 + cl; bOffH[f] = br_ * 32 + SW(br_, ks) * 8; }
#pragma unroll
    for (int f = 0; f < 2; ++f) { int br_ = (wid * 2 + f) * 16 + cl; bOffO[f] = br_ * 32 + SW(br_, ks) * 8; }

    f32x4 accH[4] = {};
    f32x4 accO[2] = {};
    for (int kc = 0; kc < 10; ++kc) {
        __syncthreads();
        if (t < 64) GLL16(aSrc, As);
        if (kc < 8) {
            GLL16(bhSrc[0], bhDst[0]); GLL16(bhSrc[1], bhDst[1]);
            GLL16(bhSrc[2], bhDst[2]); GLL16(bhSrc[3], bhDst[3]);
        }
        GLL16(boSrc[0], boDst[0]); GLL16(boSrc[1], boDst[1]);
        aSrc += 32;
#pragma unroll
        for (int j = 0; j < 4; ++j) bhSrc[j] += 32;
#pragma unroll
        for (int j = 0; j < 2; ++j) boSrc[j] += 32;
        __syncthreads();
        bf16x8 a = *(const bf16x8*)(As + aOff);
        if (kc < 8) {
#pragma unroll
            for (int f = 0; f < 4; ++f)
                accH[f] = MFMA16(a, *(const bf16x8*)(Bh + bOffH[f]), accH[f]);
        }
#pragma unroll
        for (int f = 0; f < 2; ++f)
            accO[f] = MFMA16(a, *(const bf16x8*)(Bo + bOffO[f]), accO[f]);
    }

    // head scores -> LDS; out -> global directly
#pragma unroll
    for (int f = 0; f < 4; ++f) {
        int col = (wid * 4 + f) * 16 + cl;
        float bb = bh_b[col];
#pragma unroll
        for (int r = 0; r < 4; ++r)
            sc[ks * 4 + r][col] = accH[f][r] + bb;
    }
#pragma unroll
    for (int f = 0; f < 2; ++f) {
        int col = (wid * 2 + f) * 16 + cl;
        float bb = bo[col];
#pragma unroll
        for (int r = 0; r < 4; ++r)
            outp[(size_t)(b0 + ks * 4 + r) * 128 + col] = accO[f][r] + bb;
    }
    __syncthreads();
    {   // softmax (write cols) + sigmoid/tanh (erase/add)
        int row = t >> 4, l = t & 15;
        float v[8];
#pragma unroll
        for (int j = 0; j < 8; ++j) v[j] = sc[row][l + 16 * j];
        float m = v[0];
#pragma unroll
        for (int j = 1; j < 8; ++j) m = fmaxf(m, v[j]);
#pragma unroll
        for (int mk = 8; mk >= 1; mk >>= 1) m = fmaxf(m, __shfl_xor(m, mk));
        float s = 0.f;
#pragma unroll
        for (int j = 0; j < 8; ++j) { v[j] = __expf(v[j] - m); s += v[j]; }
#pragma unroll
        for (int mk = 8; mk >= 1; mk >>= 1) s += __shfl_xor(s, mk);
        float inv = 1.f / s;
#pragma unroll
        for (int j = 0; j < 8; ++j) wL[row][l + 16 * j] = v[j] * inv;
#pragma unroll
        for (int j = 0; j < 4; ++j) eL[row][l + 16 * j] = sigf(sc[row][128 + l + 16 * j]);
#pragma unroll
        for (int j = 0; j < 4; ++j) aL[row][l + 16 * j] = tanhf(sc[row][192 + l + 16 * j]);
    }
    __syncthreads();

    // stream mem update for 16 rows
    int np = t >> 4, d4 = t & 15;
    for (int r = 0; r < 16; ++r) {
        int row = b0 + r;
        const f32x4* m4 = (const f32x4*)(mem + (size_t)row * 8192);
        f32x4* o4 = (f32x4*)(mem_new + (size_t)row * 8192);
        f32x4 e4 = *(const f32x4*)&eL[r][d4 * 4];
        f32x4 a4 = *(const f32x4*)&aL[r][d4 * 4];
#pragma unroll
        for (int j = 0; j < 8; ++j) {
            float w = wL[r][np + 16 * j];
            f32x4 m = m4[t + 256 * j];
            f32x4 rr;
            rr[0] = m[0] * (1.f - w * e4[0]) + w * a4[0];
            rr[1] = m[1] * (1.f - w * e4[1]) + w * a4[1];
            rr[2] = m[2] * (1.f - w * e4[2]) + w * a4[2];
            rr[3] = m[3] * (1.f - w * e4[3]) + w * a4[3];
            __builtin_nontemporal_store(rr, &o4[t + 256 * j]);
        }
    }
}

extern "C" void kernel_launch(void* const* d_in, const int* in_sizes, int n_in,
                              void* d_out, int out_size, void* d_ws, size_t ws_size,
                              hipStream_t stream)
{
    const float* x    = (const float*)d_in[0];
    const float* mem  = (const float*)d_in[1];
    const float* h    = (const float*)d_in[2];
    const float* c    = (const float*)d_in[3];
    const float* Wih  = (const float*)d_in[4];
    const float* Whh  = (const float*)d_in[5];
    const float* bih  = (const float*)d_in[6];
    const float* bhh  = (const float*)d_in[7];
    const float* Wr   = (const float*)d_in[8];
    const float* br   = (const float*)d_in[9];
    const float* Ww   = (const float*)d_in[10];
    const float* bw   = (const float*)d_in[11];
    const float* We   = (const float*)d_in[12];
    const float* be   = (const float*)d_in[13];
    const float* Wa   = (const float*)d_in[14];
    const float* ba   = (const float*)d_in[15];
    const float* Wo   = (const float*)d_in[16];
    const float* bo   = (const float*)d_in[17];

    float* out     = (float*)d_out;
    float* mem_new = out + 524288;
    float* h_new   = out + 34078720;
    float* c_new   = out + 35127296;

    float* ws   = (float*)d_ws;
    float* bsum = ws;                          // 1024
    float* bh_b = ws + 1024;                   // 256
    unsigned short* ub   = (unsigned short*)(ws + 1280);
    unsigned short* Ag   = ub;                 // 4096*448
    unsigned short* Aout = ub + 1835008;       // 4096*320
    unsigned short* Wg   = ub + 3145728;       // 1024*448
    unsigned short* Wh_b = ub + 3604480;       // 256*256
    unsigned short* Wo_b = ub + 3670016;       // 128*320

    kA_prep<<<256, 256, 0, stream>>>(Wih, Whh, bih, bhh, Wr, br, Ww, We, Wa, bw, be, ba,
                                     Wo, x, h, mem, Wg, bsum, Wh_b, bh_b, Wo_b, Ag, Aout);
    kB_gates<<<dim3(64, 4), 256, 0, stream>>>(Ag, Wg, bsum, c, h_new, c_new, Aout);
    kC_heads_out_mem<<<256, 256, 0, stream>>>(Aout, Wh_b, Wo_b, bh_b, bo, mem, out, mem_new);
}